// Round 4
// baseline (300.948 us; speedup 1.0000x reference)
//
#include <hip/hip_runtime.h>
#include <hip/hip_bf16.h>

// ---------- problem dims ----------
constexpr int B_ = 16, C_ = 64, F_ = 40, T_ = 512;
constexpr int D_ = F_ * C_;              // 2560
constexpr float SCALE = 0.019764235376052372f;  // 1/sqrt(2560), baked into Wq

// ---------- types ----------
typedef __attribute__((ext_vector_type(8))) short s16x8;
typedef __attribute__((ext_vector_type(4))) short s16x4;
typedef __attribute__((ext_vector_type(4))) float f32x4;

static __device__ __forceinline__ short f2bf(float f) {
  union { float f; unsigned u; } v; v.f = f;
  unsigned r = v.u + 0x7fffu + ((v.u >> 16) & 1u);   // RNE
  return (short)(r >> 16);
}

// packed fp32x2 -> bf16x2 (v_cvt_pk_bf16_f32 on gfx950), RNE
static __device__ __forceinline__ unsigned int pk2(float a, float b) {
  __hip_bfloat162 h = __float22bfloat162_rn(make_float2(a, b));
  union { __hip_bfloat162 h; unsigned int u; } cv; cv.h = h; return cv.u;
}

static __device__ __forceinline__ f32x4 mfma16(s16x8 a, s16x8 b, f32x4 c) {
  return __builtin_amdgcn_mfma_f32_16x16x32_bf16(a, b, c, 0, 0, 0);
}

// async 16B global->LDS (wave-uniform LDS base + lane*16 placement)
static __device__ __forceinline__ void gl2lds16(const short* g, short* l) {
  __builtin_amdgcn_global_load_lds(
      (const __attribute__((address_space(1))) unsigned int*)g,
      (__attribute__((address_space(3))) unsigned int*)l, 16, 0, 0);
}

// =====================================================================
// Kernel 0: convert Wq,Wk,Wv fp32 -> bf16 once.  Wq pre-scaled by SCALE.
// =====================================================================
__global__ __launch_bounds__(256) void wcvt_kernel(
    const float* __restrict__ Wq, const float* __restrict__ Wk,
    const float* __restrict__ Wv, short* __restrict__ Wb)
{
  const int i = blockIdx.x * 256 + threadIdx.x;    // granule of 4 floats
  const float* src = (i < 1024) ? Wq : (i < 2048) ? Wk : Wv;
  const float sc = (i < 1024) ? SCALE : 1.0f;
  const float4 v = *(const float4*)(src + (i & 1023) * 4);
  uint2 u; u.x = pk2(v.x * sc, v.y * sc); u.y = pk2(v.z * sc, v.w * sc);
  *(uint2*)&Wb[i * 4] = u;
}

// =====================================================================
// Kernel 1: projections, 2-tile software pipeline per block.
// Block = (b, f, th); tiles tt = th*2, th*2+1 (128 t each).
// Q,K stored [b][t][d]; V stored [b][d][t] via operand-swapped MFMA.
// =====================================================================
__global__ void proj_kernel(
    const float* __restrict__ x, const short* __restrict__ Wb,
    short* __restrict__ Q, short* __restrict__ K, short* __restrict__ V)
{
  constexpr int XS = 132;   // X lds row stride (shorts) — 0 conflicts measured
  __shared__ __align__(16) short Xl[2][64 * XS];   // 33.8 KB

  const int b = blockIdx.z, f = blockIdx.y, th = blockIdx.x;  // th: 0..1
  const int tid = threadIdx.x;
  const int w = tid >> 6, lane = tid & 63;
  const int quad = lane >> 4, c16 = lane & 15;
  const int tl = w * 32;
  const float* xbase = x + (((size_t)b * 64) * 40 + f) * 512;

  auto load_tile = [&](int tt, float4* r) {
    const float* xp = xbase + tt * 128;
    #pragma unroll
    for (int it = 0; it < 8; ++it) {
      const int i = tid + it * 256;
      r[it] = *(const float4*)(xp + (size_t)(i >> 5) * (F_ * T_) + (i & 31) * 4);
    }
  };
  auto cvt_store_tile = [&](int buf, const float4* r) {
    #pragma unroll
    for (int it = 0; it < 8; ++it) {
      const int i = tid + it * 256;
      uint2 u; u.x = pk2(r[it].x, r[it].y); u.y = pk2(r[it].z, r[it].w);
      *(uint2*)&Xl[buf][(i >> 5) * XS + (i & 31) * 4] = u;
    }
  };

  auto process_tile = [&](int buf, int tt) {
    // X fragments, shared by all three projections.
    s16x8 bfrag[2][2];
    #pragma unroll
    for (int ni = 0; ni < 2; ++ni)
      #pragma unroll
      for (int ks = 0; ks < 2; ++ks) {
        const int t = tl + ni * 16 + c16;
        const int cb = ks * 32 + quad * 8;
        s16x8 tmp;
        #pragma unroll
        for (int j = 0; j < 8; ++j) tmp[j] = Xl[buf][(cb + j) * XS + t];
        bfrag[ni][ks] = tmp;
      }
    #pragma unroll
    for (int p = 0; p < 3; ++p) {
      const short* Wp = Wb + p * 4096;
      s16x8 wfrag[4][2];
      #pragma unroll
      for (int mi = 0; mi < 4; ++mi)
        #pragma unroll
        for (int ks = 0; ks < 2; ++ks)
          wfrag[mi][ks] = *(const s16x8*)(Wp + (mi * 16 + c16) * 64 + ks * 32 + quad * 8);

      if (p < 2) {
        f32x4 acc[4][2] = {};   // D[m=o][n=t]
        #pragma unroll
        for (int ks = 0; ks < 2; ++ks)
          #pragma unroll
          for (int mi = 0; mi < 4; ++mi)
            #pragma unroll
            for (int ni = 0; ni < 2; ++ni)
              acc[mi][ni] = mfma16(wfrag[mi][ks], bfrag[ni][ks], acc[mi][ni]);
        short* outp = (p == 0) ? Q : K;
        #pragma unroll
        for (int mi = 0; mi < 4; ++mi)
          #pragma unroll
          for (int ni = 0; ni < 2; ++ni) {
            const int t = tt * 128 + tl + ni * 16 + c16;
            const int o = mi * 16 + quad * 4;
            uint2 u;
            u.x = pk2(acc[mi][ni][0], acc[mi][ni][1]);
            u.y = pk2(acc[mi][ni][2], acc[mi][ni][3]);
            *(uint2*)&outp[((size_t)(b * 512 + t)) * D_ + f * 64 + o] = u;
          }
      } else {
        f32x4 acc[2][4] = {};   // swapped: D[m=t][n=o]
        #pragma unroll
        for (int ks = 0; ks < 2; ++ks)
          #pragma unroll
          for (int ni = 0; ni < 2; ++ni)
            #pragma unroll
            for (int mi = 0; mi < 4; ++mi)
              acc[ni][mi] = mfma16(bfrag[ni][ks], wfrag[mi][ks], acc[ni][mi]);
        #pragma unroll
        for (int ni = 0; ni < 2; ++ni)
          #pragma unroll
          for (int mi = 0; mi < 4; ++mi) {
            const int t = tt * 128 + tl + ni * 16 + quad * 4;
            const int o = mi * 16 + c16;
            uint2 u;
            u.x = pk2(acc[ni][mi][0], acc[ni][mi][1]);
            u.y = pk2(acc[ni][mi][2], acc[ni][mi][3]);
            *(uint2*)&V[((size_t)(b * D_ + f * 64 + o)) * 512 + t] = u;
          }
      }
    }
  };

  float4 r0[8], r1[8];
  load_tile(th * 2, r0);
  cvt_store_tile(0, r0);
  __syncthreads();
  load_tile(th * 2 + 1, r1);       // in flight during tile-0 compute
  process_tile(0, th * 2);
  cvt_store_tile(1, r1);
  __syncthreads();
  process_tile(1, th * 2 + 1);
}

// =====================================================================
// Kernel 2: S = Qs K^T (scale baked into Qs).  128x128 tile, 512 threads
// (8 waves, 4x2), BK=64, DOUBLE-buffered gl2lds staging w/ XOR swizzle.
// XCD-swizzled block id: 4 nt-blocks of one (b,mt) share an XCD (Q-tile
// L2 reuse).
// =====================================================================
__global__ __launch_bounds__(512) void scores_kernel(
    const short* __restrict__ Q, const short* __restrict__ K,
    float* __restrict__ S)
{
  __shared__ __align__(16) short As[2][128 * 64];   // 32 KB
  __shared__ __align__(16) short Bs[2][128 * 64];   // 32 KB

  const int flat = blockIdx.x;                 // 0..255
  const int rr = flat & 7, qq = flat >> 3;
  const int nt = qq & 3, p = (qq >> 2) * 8 + rr;   // p = b*4+mt
  const int b = p >> 2, mt = p & 3;
  const int m0 = mt * 128, n0 = nt * 128;

  const int tid = threadIdx.x;
  const int w = tid >> 6, lane = tid & 63, quad = lane >> 4, c16 = lane & 15;
  const int wm = (w >> 1) * 32, wn = (w & 1) * 64;

  const short* qb = Q + (size_t)(b * 512 + m0) * D_;
  const short* kb = K + (size_t)(b * 512 + n0) * D_;

  const short* agp[2]; const short* bgp[2]; int soff[2];
  #pragma unroll
  for (int i = 0; i < 2; ++i) {
    const int s = i * 512 + tid, row = s >> 3;
    const int g = (s & 7) ^ (row & 7);
    agp[i] = qb + (size_t)row * D_ + g * 8;
    bgp[i] = kb + (size_t)row * D_ + g * 8;
    soff[i] = (i * 512 + w * 64) * 8;          // wave-uniform LDS base (shorts)
  }

  int amoff[2][2], bmoff[4][2];
  #pragma unroll
  for (int mi = 0; mi < 2; ++mi)
    #pragma unroll
    for (int ks = 0; ks < 2; ++ks) {
      const int row = wm + mi * 16 + c16;
      amoff[mi][ks] = row * 64 + (((ks * 4 + quad) ^ (row & 7)) * 8);
    }
  #pragma unroll
  for (int ni = 0; ni < 4; ++ni)
    #pragma unroll
    for (int ks = 0; ks < 2; ++ks) {
      const int row = wn + ni * 16 + c16;
      bmoff[ni][ks] = row * 64 + (((ks * 4 + quad) ^ (row & 7)) * 8);
    }

  f32x4 acc[2][4] = {};
  constexpr int NK = D_ / 64;   // 40

  // prologue: stage k-tile 0 into buf 0
  #pragma unroll
  for (int i = 0; i < 2; ++i) {
    gl2lds16(agp[i], &As[0][soff[i]]);
    gl2lds16(bgp[i], &Bs[0][soff[i]]);
  }

  for (int kk = 0; kk < NK; ++kk) {
    const int buf = kk & 1;
    __syncthreads();                       // drains loads issued LAST iter
    if (kk + 1 < NK) {                     // prefetch next k-tile, other buf
      const int ko = (kk + 1) * 64;
      #pragma unroll
      for (int i = 0; i < 2; ++i) {
        gl2lds16(agp[i] + ko, &As[buf ^ 1][soff[i]]);
        gl2lds16(bgp[i] + ko, &Bs[buf ^ 1][soff[i]]);
      }
    }
    s16x8 am[2][2], bm[4][2];
    #pragma unroll
    for (int mi = 0; mi < 2; ++mi)
      #pragma unroll
      for (int ks = 0; ks < 2; ++ks) am[mi][ks] = *(const s16x8*)&As[buf][amoff[mi][ks]];
    #pragma unroll
    for (int ni = 0; ni < 4; ++ni)
      #pragma unroll
      for (int ks = 0; ks < 2; ++ks) bm[ni][ks] = *(const s16x8*)&Bs[buf][bmoff[ni][ks]];
    #pragma unroll
    for (int ks = 0; ks < 2; ++ks)
      #pragma unroll
      for (int mi = 0; mi < 2; ++mi)
        #pragma unroll
        for (int ni = 0; ni < 4; ++ni)
          acc[mi][ni] = mfma16(am[mi][ks], bm[ni][ks], acc[mi][ni]);
  }

  float* sp = S + (size_t)b * 512 * 512;
  #pragma unroll
  for (int mi = 0; mi < 2; ++mi)
    #pragma unroll
    for (int ni = 0; ni < 4; ++ni) {
      const int kcol = n0 + wn + ni * 16 + c16;
      const int qr = m0 + wm + mi * 16 + quad * 4;
      #pragma unroll
      for (int r = 0; r < 4; ++r)
        sp[(size_t)(qr + r) * 512 + kcol] = acc[mi][ni][r];
    }
}

// =====================================================================
// Kernel 3: row softmax, S fp32 -> A bf16.  One WAVE per (b,q) row.
// =====================================================================
__global__ __launch_bounds__(256) void softmax_kernel(
    const float* __restrict__ S, short* __restrict__ A)
{
  const int b = blockIdx.y;
  const int tid = threadIdx.x, w = tid >> 6, lane = tid & 63;
  const int q = blockIdx.x * 4 + w;
  const float* row = S + ((size_t)b * 512 + q) * 512;

  const float4 v0 = *(const float4*)(row + lane * 4);
  const float4 v1 = *(const float4*)(row + 256 + lane * 4);
  float e[8] = {v0.x, v0.y, v0.z, v0.w, v1.x, v1.y, v1.z, v1.w};

  float m = e[0];
  #pragma unroll
  for (int i = 1; i < 8; ++i) m = fmaxf(m, e[i]);
  #pragma unroll
  for (int off = 1; off < 64; off <<= 1) m = fmaxf(m, __shfl_xor(m, off));

  float s = 0.f;
  #pragma unroll
  for (int i = 0; i < 8; ++i) { e[i] = __expf(e[i] - m); s += e[i]; }
  #pragma unroll
  for (int off = 1; off < 64; off <<= 1) s += __shfl_xor(s, off);

  const float inv = 1.0f / s;
  short* arow = A + ((size_t)b * 512 + q) * 512;
  uint2 o0, o1;
  o0.x = pk2(e[0] * inv, e[1] * inv); o0.y = pk2(e[2] * inv, e[3] * inv);
  o1.x = pk2(e[4] * inv, e[5] * inv); o1.y = pk2(e[6] * inv, e[7] * inv);
  *(uint2*)&arow[lane * 4] = o0;
  *(uint2*)&arow[256 + lane * 4] = o1;
}

// =====================================================================
// Kernel 4: out = A @ V.  128x128 tile, BK=64, gl2lds + swizzle.
// XCD-swizzled block id: 20 dt-blocks of one (b,mt) share an XCD so the
// A-tile (read 20x) stays in that XCD's L2.
// =====================================================================
__global__ __launch_bounds__(256) void pv_kernel(
    const short* __restrict__ A, const short* __restrict__ V,
    float* __restrict__ out)
{
  __shared__ __align__(16) short As[128 * 64];   // 16 KB
  __shared__ __align__(16) short Bs[128 * 64];   // 16 KB

  const int flat = blockIdx.x;                   // 0..1279
  const int rr = flat & 7, qq = flat >> 3;
  const int dt = qq % 20, p = (qq / 20) * 8 + rr;  // p = b*4+mt
  const int b = p >> 2, mt = p & 3;
  const int m0 = mt * 128, n0 = dt * 128;

  const int tid = threadIdx.x;
  const int w = tid >> 6, lane = tid & 63, quad = lane >> 4, c16 = lane & 15;
  const int wm = (w >> 1) * 64, wn = (w & 1) * 64;

  const short* ab = A + ((size_t)b * 512 + m0) * 512;
  const short* vb = V + ((size_t)b * D_ + n0) * 512;

  const short* agp[4]; short* aldsb[4];
  const short* bgp[4]; short* bldsb[4];
  #pragma unroll
  for (int i = 0; i < 4; ++i) {
    const int s = i * 256 + tid, row = s >> 3;
    const int g = (s & 7) ^ (row & 7);
    agp[i] = ab + (size_t)row * 512 + g * 8;
    bgp[i] = vb + (size_t)row * 512 + g * 8;
    aldsb[i] = &As[(i * 256 + w * 64) * 8];
    bldsb[i] = &Bs[(i * 256 + w * 64) * 8];
  }

  const short* amp[4][2];
  const short* bmp[4][2];
  #pragma unroll
  for (int mi = 0; mi < 4; ++mi)
    #pragma unroll
    for (int ks = 0; ks < 2; ++ks) {
      const int rowa = wm + mi * 16 + c16;
      const int rowb = wn + mi * 16 + c16;
      amp[mi][ks] = &As[rowa * 64 + (((ks * 4 + quad) ^ (rowa & 7)) * 8)];
      bmp[mi][ks] = &Bs[rowb * 64 + (((ks * 4 + quad) ^ (rowb & 7)) * 8)];
    }

  f32x4 acc[4][4] = {};
  constexpr int NK = 512 / 64;   // 8
  for (int kk = 0; kk < NK; ++kk) {
    const int ko = kk * 64;
    __syncthreads();
    #pragma unroll
    for (int i = 0; i < 4; ++i) gl2lds16(agp[i] + ko, aldsb[i]);
    #pragma unroll
    for (int i = 0; i < 4; ++i) gl2lds16(bgp[i] + ko, bldsb[i]);
    __syncthreads();
    s16x8 am[4][2], bm[4][2];
    #pragma unroll
    for (int mi = 0; mi < 4; ++mi)
      #pragma unroll
      for (int ks = 0; ks < 2; ++ks) {
        am[mi][ks] = *(const s16x8*)amp[mi][ks];
        bm[mi][ks] = *(const s16x8*)bmp[mi][ks];
      }
    #pragma unroll
    for (int ks = 0; ks < 2; ++ks)
      #pragma unroll
      for (int mi = 0; mi < 4; ++mi)
        #pragma unroll
        for (int ni = 0; ni < 4; ++ni)
          acc[mi][ni] = mfma16(am[mi][ks], bm[ni][ks], acc[mi][ni]);
  }

  #pragma unroll
  for (int mi = 0; mi < 4; ++mi)
    #pragma unroll
    for (int ni = 0; ni < 4; ++ni) {
      const int d = n0 + wn + ni * 16 + c16;
      const int ff = d >> 6, cc = d & 63;
      const int t = m0 + wm + mi * 16 + quad * 4;
      float4 o4;
      o4.x = acc[mi][ni][0]; o4.y = acc[mi][ni][1];
      o4.z = acc[mi][ni][2]; o4.w = acc[mi][ni][3];
      *(float4*)&out[(((size_t)b * 64 + cc) * 40 + ff) * 512 + t] = o4;
    }
}

// =====================================================================
extern "C" void kernel_launch(void* const* d_in, const int* in_sizes, int n_in,
                              void* d_out, int out_size, void* d_ws, size_t ws_size,
                              hipStream_t stream)
{
  const float* x  = (const float*)d_in[0];
  const float* Wq = (const float*)d_in[1];
  const float* Wk = (const float*)d_in[2];
  const float* Wv = (const float*)d_in[3];
  float* out = (float*)d_out;

  char* ws = (char*)d_ws;
  constexpr size_t QB = (size_t)B_ * T_ * D_ * 2;
  short* Q  = (short*)(ws);
  short* Kt = (short*)(ws + QB);
  short* Vt = (short*)(ws + 2 * QB);
  float* S  = (float*)(ws + 3 * QB);
  short* Wb = (short*)(ws + 3 * QB);   // overlaps S (sequential lifetime)
  short* At = (short*)(ws + 3 * QB + (size_t)B_ * T_ * T_ * 4);

  wcvt_kernel<<<dim3(12), 256, 0, stream>>>(Wq, Wk, Wv, Wb);
  proj_kernel<<<dim3(2, 40, 16), 256, 0, stream>>>(x, Wb, Q, Kt, Vt);
  scores_kernel<<<dim3(256), 512, 0, stream>>>(Q, Kt, S);
  softmax_kernel<<<dim3(128, 16), 256, 0, stream>>>(S, At);
  pv_kernel<<<dim3(1280), 256, 0, stream>>>(At, Vt, out);
}